// Round 15
// baseline (363.896 us; speedup 1.0000x reference)
//
#include <hip/hip_runtime.h>

typedef __attribute__((ext_vector_type(8))) short short8;   // 8 bf16
typedef __attribute__((ext_vector_type(4))) float f32x4;

__device__ inline ushort f2bf(float f) {
    union { float f; unsigned u; } v{f};
    unsigned r = v.u + 0x7FFF + ((v.u >> 16) & 1);
    return (ushort)(r >> 16);
}
__device__ inline float bf2f(ushort u) {
    union { unsigned u; float f; } v;
    v.u = ((unsigned)u) << 16;
    return v.f;
}

// CK-style addrspace casts (low 32 bits of a flat LDS address == LDS offset).
__device__ inline void gload_lds16(const void* g, void* l) {
    __builtin_amdgcn_global_load_lds(
        (const __attribute__((address_space(1))) unsigned int*)(uintptr_t)g,
        (__attribute__((address_space(3))) unsigned int*)(uintptr_t)l,
        16, 0, 0);
}

// ---------------------------------------------------------------------------
// prep: merged weight-convert (blocks 0..895) + sen convert/transpose
// (blocks 896..2175).
// ---------------------------------------------------------------------------
__global__ __launch_bounds__(256) void prep_kernel(
    const float* __restrict__ s1, const float* __restrict__ s2,
    const float* __restrict__ W0, const float* __restrict__ b0,
    const float* __restrict__ W1, const float* __restrict__ b1,
    const float* __restrict__ W2, const float* __restrict__ b2,
    const float* __restrict__ W3, const float* __restrict__ b3,
    ushort* __restrict__ Senb, ushort* __restrict__ St1, ushort* __restrict__ St2,
    ushort* __restrict__ Wb0, float* __restrict__ bp0,
    ushort* __restrict__ Wb1, float* __restrict__ bp1,
    ushort* __restrict__ Wb2, float* __restrict__ bp2,
    ushort* __restrict__ Wb3, float* __restrict__ bp3)
{
    const int bid = blockIdx.x;
    if (bid < 896) {
        const int mat = bid / 224, n = bid % 224;
        if (mat == 2) {   // G1 split layout [224][640]
            for (int k = threadIdx.x; k < 640; k += 256) {
                float v = 0.f;
                if (n < 200) {
                    if (k < 320) { if (k < 300) v = W2[(size_t)n * 600 + k]; }
                    else { int cc = k - 320; if (cc < 300) v = W2[(size_t)n * 600 + 300 + cc]; }
                }
                Wb2[(size_t)n * 640 + k] = f2bf(v);
            }
            if (threadIdx.x == 0) bp2[n] = (n < 200) ? b2[n] : 0.f;
            return;
        }
        const float* W; const float* b; ushort* Wb; float* bp; int N, K, KP;
        if (mat == 0)      { W = W0; b = b0; Wb = Wb0; bp = bp0; N = 200; K = 300; KP = 320; }
        else if (mat == 1) { W = W1; b = b1; Wb = Wb1; bp = bp1; N = 200; K = 200; KP = 224; }
        else               { W = W3; b = b3; Wb = Wb3; bp = bp3; N = 200; K = 200; KP = 224; }
        for (int k = threadIdx.x; k < KP; k += 256)
            Wb[(size_t)n * KP + k] = (n < N && k < K) ? f2bf(W[(size_t)n * K + k]) : (ushort)0;
        if (threadIdx.x == 0) bp[n] = (n < N) ? b[n] : 0.f;
        return;
    }
    // sen path
    const int sb = bid - 896;
    const int gx = sb & 127;
    const int rest = sb >> 7;          // 0..9
    const int gy = rest % 5, gz = rest / 5;
    const float* X = gz ? s2 : s1;
    ushort* Xt = gz ? St2 : St1;
    ushort* Sb = Senb + (size_t)gz * 8192 * 320;
    __shared__ float t[64][65];
    const int r0 = gx * 64, c0 = gy * 64;
    const int tc = threadIdx.x & 63, tr = threadIdx.x >> 6;
    for (int rr = tr; rr < 64; rr += 4) {
        int c = c0 + tc;
        float v = (c < 300) ? X[(size_t)(r0 + rr) * 300 + c] : 0.f;
        t[rr][tc] = v;
        if (c < 320) Sb[(size_t)(r0 + rr) * 320 + c] = f2bf(v);
    }
    __syncthreads();
    for (int rr = tr; rr < 64; rr += 4) {
        int oc = c0 + rr;
        if (oc < 320)
            Xt[(size_t)oc * 8192 + r0 + tc] = f2bf(t[tc][rr]);
    }
}

// ---------------------------------------------------------------------------
// Fused 2-layer MLP (F): Y = relu(relu(X@W1^T+b1)@W2^T+b2) -> bf16 [M][224].
// One wave, 16 rows/block (R13 form; R14's K-split was neutral).
// ---------------------------------------------------------------------------
__global__ __launch_bounds__(64) void mlp2_kernel(
    const ushort* __restrict__ X,
    const ushort* __restrict__ W1, const float* __restrict__ b1,
    const ushort* __restrict__ W2, const float* __restrict__ b2,
    ushort* __restrict__ Ybf)
{
    const int r0 = blockIdx.x * 16;
    const int lane = threadIdx.x;
    const int lr = lane & 15, lg = lane >> 4;

    __shared__ __align__(16) ushort Y1[16][232];

    f32x4 a1[14];
#pragma unroll
    for (int t = 0; t < 14; ++t) a1[t] = f32x4{0.f, 0.f, 0.f, 0.f};

    const ushort* Xrow = X + (size_t)(r0 + lr) * 320 + lg * 8;
    const ushort* W1r  = W1 + (size_t)lr * 320 + lg * 8;
    for (int k0 = 0; k0 < 320; k0 += 32) {
        short8 a = *(const short8*)(Xrow + k0);
#pragma unroll
        for (int t = 0; t < 14; ++t) {
            short8 bfr = *(const short8*)(W1r + (size_t)t * 16 * 320 + k0);
            a1[t] = __builtin_amdgcn_mfma_f32_16x16x32_bf16(a, bfr, a1[t], 0, 0, 0);
        }
    }
#pragma unroll
    for (int t = 0; t < 14; ++t) {
        int col = t * 16 + lr;
        float bv = b1[col];
#pragma unroll
        for (int rr = 0; rr < 4; ++rr)
            Y1[lg * 4 + rr][col] = f2bf(fmaxf(a1[t][rr] + bv, 0.f));
    }
    __syncthreads();

    f32x4 a2[14];
#pragma unroll
    for (int t = 0; t < 14; ++t) a2[t] = f32x4{0.f, 0.f, 0.f, 0.f};
    const ushort* W2r = W2 + (size_t)lr * 224 + lg * 8;
    for (int k0 = 0; k0 < 224; k0 += 32) {
        short8 a = *(const short8*)&Y1[lr][lg * 8 + k0];
#pragma unroll
        for (int t = 0; t < 14; ++t) {
            short8 bfr = *(const short8*)(W2r + (size_t)t * 16 * 224 + k0);
            a2[t] = __builtin_amdgcn_mfma_f32_16x16x32_bf16(a, bfr, a2[t], 0, 0, 0);
        }
    }
#pragma unroll
    for (int t = 0; t < 14; ++t) {
        int col = t * 16 + lr;
        float bv = b2[col];
#pragma unroll
        for (int rr = 0; rr < 4; ++rr) {
            int row = r0 + lg * 4 + rr;
            Ybf[(size_t)row * 224 + col] = f2bf(fmaxf(a2[t][rr] + bv, 0.f));
        }
    }
}

// ---------------------------------------------------------------------------
// G-MLP with FUSED 4-slice combine (input = [senb | (sum_q Pacc_q)*inv],
// Pacc bf16) and FUSED column-sum epilogue -> Part[block][200] f32.
// ---------------------------------------------------------------------------
__global__ __launch_bounds__(64) void gmlp2_kernel(
    const ushort* __restrict__ Senb,
    const ushort* __restrict__ Pacc, const float* __restrict__ Dpart,
    const ushort* __restrict__ W1, const float* __restrict__ b1,
    const ushort* __restrict__ W2, const float* __restrict__ b2,
    float* __restrict__ Part)
{
    const int r0 = blockIdx.x * 16;
    const int lane = threadIdx.x;
    const int lr = lane & 15, lg = lane >> 4;
    const int row = r0 + lr;

    __shared__ __align__(16) ushort Y1[16][232];

    const float inv = 1.f / (Dpart[row] + Dpart[16384 + row] +
                             Dpart[2 * 16384 + row] + Dpart[3 * 16384 + row]);
    const ushort* pa = Pacc + (size_t)row * 320;

    f32x4 a1[14];
#pragma unroll
    for (int t = 0; t < 14; ++t) a1[t] = f32x4{0.f, 0.f, 0.f, 0.f};

    const ushort* Xrow = Senb + (size_t)row * 320 + lg * 8;
    const ushort* W1r  = W1 + (size_t)lr * 640 + lg * 8;
    for (int k0 = 0; k0 < 640; k0 += 32) {
        short8 a;
        if (k0 < 320) {
            a = *(const short8*)(Xrow + k0);
        } else {
            int kk = k0 - 320 + lg * 8;
            short8 x0 = *(const short8*)(pa + kk);
            short8 x1 = *(const short8*)(pa + (size_t)16384 * 320 + kk);
            short8 x2 = *(const short8*)(pa + (size_t)2 * 16384 * 320 + kk);
            short8 x3 = *(const short8*)(pa + (size_t)3 * 16384 * 320 + kk);
#pragma unroll
            for (int m = 0; m < 8; ++m) {
                float s = bf2f((ushort)x0[m]) + bf2f((ushort)x1[m]) +
                          bf2f((ushort)x2[m]) + bf2f((ushort)x3[m]);
                a[m] = (short)f2bf(s * inv);
            }
        }
#pragma unroll
        for (int t = 0; t < 14; ++t) {
            short8 bfr = *(const short8*)(W1r + (size_t)t * 16 * 640 + k0);
            a1[t] = __builtin_amdgcn_mfma_f32_16x16x32_bf16(a, bfr, a1[t], 0, 0, 0);
        }
    }
#pragma unroll
    for (int t = 0; t < 14; ++t) {
        int col = t * 16 + lr;
        float bv = b1[col];
#pragma unroll
        for (int rr = 0; rr < 4; ++rr)
            Y1[lg * 4 + rr][col] = f2bf(fmaxf(a1[t][rr] + bv, 0.f));
    }
    __syncthreads();

    f32x4 a2[14];
#pragma unroll
    for (int t = 0; t < 14; ++t) a2[t] = f32x4{0.f, 0.f, 0.f, 0.f};
    const ushort* W2r = W2 + (size_t)lr * 224 + lg * 8;
    for (int k0 = 0; k0 < 224; k0 += 32) {
        short8 a = *(const short8*)&Y1[lr][lg * 8 + k0];
#pragma unroll
        for (int t = 0; t < 14; ++t) {
            short8 bfr = *(const short8*)(W2r + (size_t)t * 16 * 224 + k0);
            a2[t] = __builtin_amdgcn_mfma_f32_16x16x32_bf16(a, bfr, a2[t], 0, 0, 0);
        }
    }
#pragma unroll
    for (int t = 0; t < 14; ++t) {
        int col = t * 16 + lr;
        if (col < 200) {
            float bv = b2[col];
            float s = 0.f;
#pragma unroll
            for (int rr = 0; rr < 4; ++rr)
                s += fmaxf(a2[t][rr] + bv, 0.f);
            s += __shfl_xor(s, 16);
            s += __shfl_xor(s, 32);
            if (lg == 0)
                Part[(size_t)blockIdx.x * 200 + col] = s;
        }
    }
}

// ---------------------------------------------------------------------------
// Flash attend, 4-way j-split, 128 Q-rows x 2048 j per block, 512 thr =
// 8 waves, grid 512 = 2 blocks/CU (4 waves/SIMD). LDS 77.8 KB (< 80 KB).
// Sl dropped (R14 analysis: single lockstep block left the LDS pipe at 68%
// utilization; co-residency needs < 80 KB) — St read direct from L2 into
// registers (R10-proven pattern). B tile stays LDS-staged (the R11 dedup).
// ---------------------------------------------------------------------------
__global__ __launch_bounds__(512, 2) void attend_mfma_kernel(
    const ushort* __restrict__ FaFb, const ushort* __restrict__ St1,
    const ushort* __restrict__ St2, ushort* __restrict__ Pacc,
    float* __restrict__ Dpart)
{
    const int b = blockIdx.x;
    const int it  = b & 63;
    const int jq  = (b >> 6) & 3;
    const int dir = b >> 8;
    const ushort* A  = FaFb + (dir ? (size_t)8192 * 224 : 0);
    const ushort* B  = FaFb + (dir ? 0 : (size_t)8192 * 224);
    const ushort* St = dir ? St1 : St2;
    const int ib = it * 128;
    const int jo = jq * 2048;

    const int tid = threadIdx.x;
    const int w = tid >> 6;                 // 0..7
    const int wi = w >> 1, wj = w & 1;      // E roles
    const int dq = w & 3,  ih = w >> 2;     // PV roles
    const int lane = tid & 63;
    const int lr = lane & 15, lg = lane >> 4;

    __shared__ __align__(16) ushort Bl[2][28 * 512];   // 57,344 B
    __shared__ __align__(16) ushort Pl[128][76];       // 19,456 B
    __shared__ float dled[8][32];                      //  1,024 B  (77,824)

    f32x4 acc[4][5];
#pragma unroll
    for (int s = 0; s < 4; ++s)
#pragma unroll
        for (int t = 0; t < 5; ++t) acc[s][t] = f32x4{0.f, 0.f, 0.f, 0.f};
    float dsum[2] = {0.f, 0.f};

    // A fragments: rows i = ib + wi*32 + si*16 + lr
    short8 afr[2][7];
#pragma unroll
    for (int si = 0; si < 2; ++si) {
        const ushort* Ar = A + (size_t)(ib + wi * 32 + si * 16 + lr) * 224 + lg * 8;
#pragma unroll
        for (int k = 0; k < 7; ++k) afr[si][k] = *(const short8*)(Ar + k * 32);
    }

    // B staging descriptors (28 chunks of 1024 B, frag layout)
    const int nB = (w < 4) ? 4 : 3;
    const int pB = (w < 4) ? (w * 4) : (16 + (w - 4) * 3);
    int boff[4];
#pragma unroll
    for (int q = 0; q < 4; ++q) {
        int p = pB + q;
        boff[q] = ((p / 7) * 16 + lr) * 448 + ((p % 7) * 32 + lg * 8) * 2;
    }
    const char* Bb = (const char*)B + (size_t)jo * 448;

    // St source for PV role (dq): row d = dq*80 + t*16 + lr, col jb+h*32+lg*8
    const ushort* Sbase = St + (size_t)(dq * 80 + lr) * 8192 + jo + lg * 8;

    // prologue: stage B(0) -> Bl[0]
#pragma unroll
    for (int q = 0; q < 4; ++q)
        if (q < nB) gload_lds16(Bb + boff[q], &Bl[0][(pB + q) * 512]);
    __syncthreads();

    int buf = 0;
    for (int jb = 0; jb < 2048; jb += 64, buf ^= 1) {
        // issue St h0 loads early (consumed in PV after barrier1)
        short8 st0[5];
#pragma unroll
        for (int t = 0; t < 5; ++t)
            st0[t] = *(const short8*)(Sbase + (size_t)t * 16 * 8192 + jb);

        // ---- E (swapped): wave (wi,wj) computes E[32 i x 32 j] ----
        f32x4 e[2][2];
#pragma unroll
        for (int si = 0; si < 2; ++si)
#pragma unroll
            for (int jt = 0; jt < 2; ++jt) e[si][jt] = f32x4{0.f, 0.f, 0.f, 0.f};
        __builtin_amdgcn_s_setprio(1);
#pragma unroll
        for (int kk = 0; kk < 7; ++kk) {
            short8 b0 = *(const short8*)&Bl[buf][((2 * wj + 0) * 7 + kk) * 512 + lane * 8];
            short8 b1 = *(const short8*)&Bl[buf][((2 * wj + 1) * 7 + kk) * 512 + lane * 8];
            e[0][0] = __builtin_amdgcn_mfma_f32_16x16x32_bf16(b0, afr[0][kk], e[0][0], 0, 0, 0);
            e[1][0] = __builtin_amdgcn_mfma_f32_16x16x32_bf16(b0, afr[1][kk], e[1][0], 0, 0, 0);
            e[0][1] = __builtin_amdgcn_mfma_f32_16x16x32_bf16(b1, afr[0][kk], e[0][1], 0, 0, 0);
            e[1][1] = __builtin_amdgcn_mfma_f32_16x16x32_bf16(b1, afr[1][kk], e[1][1], 0, 0, 0);
        }
        __builtin_amdgcn_s_setprio(0);

        // issue St h1 loads (consumed in PV h1)
        short8 st1[5];
#pragma unroll
        for (int t = 0; t < 5; ++t)
            st1[t] = *(const short8*)(Sbase + (size_t)t * 16 * 8192 + jb + 32);

        // exp; packed b64 P-writes (lane lr = i, reg = j)
#pragma unroll
        for (int si = 0; si < 2; ++si) {
#pragma unroll
            for (int jt = 0; jt < 2; ++jt) {
                float x0 = __expf(e[si][jt][0]);
                float x1 = __expf(e[si][jt][1]);
                float x2 = __expf(e[si][jt][2]);
                float x3 = __expf(e[si][jt][3]);
                dsum[si] += (x0 + x1) + (x2 + x3);
                uint2 pk;
                pk.x = (unsigned)f2bf(x0) | ((unsigned)f2bf(x1) << 16);
                pk.y = (unsigned)f2bf(x2) | ((unsigned)f2bf(x3) << 16);
                *(uint2*)&Pl[wi * 32 + si * 16 + lr][wj * 32 + jt * 16 + lg * 4] = pk;
            }
        }
        __syncthreads();   // barrier1: Pl ready; Bl[buf] consumed

        // stage next B tile into Bl[buf^1]; drained by barrier2 (PV covers)
        if (jb + 64 < 2048) {
            const char* Bn = Bb + (size_t)(jb + 64) * 448;
#pragma unroll
            for (int q = 0; q < 4; ++q)
                if (q < nB) gload_lds16(Bn + boff[q], &Bl[buf ^ 1][(pB + q) * 512]);
        }

        // ---- PV: wave (dq,ih) computes O[64 i x 80 d] over these 64 j ----
        {
            short8 pf[4];
#pragma unroll
            for (int s = 0; s < 4; ++s)
                pf[s] = *(const short8*)&Pl[ih * 64 + s * 16 + lr][lg * 8];
            __builtin_amdgcn_s_setprio(1);
#pragma unroll
            for (int s = 0; s < 4; ++s)
#pragma unroll
                for (int t = 0; t < 5; ++t)
                    acc[s][t] = __builtin_amdgcn_mfma_f32_16x16x32_bf16(pf[s], st0[t], acc[s][t], 0, 0, 0);
            __builtin_amdgcn_s_setprio(0);
#pragma unroll
            for (int s = 0; s < 4; ++s)
                pf[s] = *(const short8*)&Pl[ih * 64 + s * 16 + lr][32 + lg * 8];
            __builtin_amdgcn_s_setprio(1);
#pragma unroll
            for (int s = 0; s < 4; ++s)
#pragma unroll
                for (int t = 0; t < 5; ++t)
                    acc[s][t] = __builtin_amdgcn_mfma_f32_16x16x32_bf16(pf[s], st1[t], acc[s][t], 0, 0, 0);
            __builtin_amdgcn_s_setprio(0);
        }
        __syncthreads();   // barrier2: Pl consumed; B staging drained
    }

    // denominator: lane lr holds row-partials; reduce over lg groups.
#pragma unroll
    for (int si = 0; si < 2; ++si) {
        dsum[si] += __shfl_xor(dsum[si], 16);
        dsum[si] += __shfl_xor(dsum[si], 32);
    }
    if (lg == 0) {
#pragma unroll
        for (int si = 0; si < 2; ++si)
            dled[w][si * 16 + lr] = dsum[si];
    }
    __syncthreads();

    // Dpart[jq][dir*8192 + ib + i], i in [0,128): sum the wj pair
    if (tid < 128) {
        int wi2 = tid >> 5, idx = tid & 31;
        Dpart[(size_t)jq * 16384 + dir * 8192 + ib + tid] =
            dled[wi2 * 2][idx] + dled[wi2 * 2 + 1][idx];
    }

    // raw partials (bf16): Pacc[jq][dir*8192 + i][d]
    ushort* Pb = Pacc + ((size_t)jq * 16384 + dir * 8192 + ib + ih * 64) * 320;
#pragma unroll
    for (int t = 0; t < 5; ++t) {
        int d = dq * 80 + t * 16 + lr;
#pragma unroll
        for (int s = 0; s < 4; ++s)
#pragma unroll
            for (int r = 0; r < 4; ++r)
                Pb[(size_t)(s * 16 + lg * 4 + r) * 320 + d] = f2bf(acc[s][t][r]);
    }
}

// ---------------------------------------------------------------------------
// tail: fused partial-colsum + H head + softmax. One 1024-thread block.
// ---------------------------------------------------------------------------
__global__ __launch_bounds__(1024) void tail_kernel(
    const float* __restrict__ Part,
    const float* __restrict__ Hw1, const float* __restrict__ Hb1,
    const float* __restrict__ Hw2, const float* __restrict__ Hb2,
    float* __restrict__ out)
{
    __shared__ float hpart[800];
    __shared__ float hx[400];
    __shared__ float hr[200];
    __shared__ float lgts[3];
    const int tid = threadIdx.x;

    if (tid < 800) {
        int oc = tid >> 1, ph = tid & 1;
        const float* base = Part + ((size_t)((oc < 200 ? 0 : 512) + ph * 256)) * 200 + (oc % 200);
        float s = 0.f;
        for (int q = 0; q < 256; ++q) s += base[(size_t)q * 200];
        hpart[tid] = s;
    }
    __syncthreads();
    if (tid < 400) hx[tid] = hpart[2 * tid] + hpart[2 * tid + 1];
    __syncthreads();

    {
        int r = tid >> 2, p = tid & 3;
        float a = 0.f;
        if (r < 200) {
            for (int kk = 0; kk < 100; ++kk) {
                int k = p + 4 * kk;
                a = fmaf(hx[k], Hw1[r * 400 + k], a);
            }
        }
        a += __shfl_xor(a, 1);
        a += __shfl_xor(a, 2);
        if (p == 0 && r < 200) hr[r] = fmaxf(a + Hb1[r], 0.f);
    }
    __syncthreads();

    if (tid < 192) {
        int o = tid >> 6, ln = tid & 63;
        float a = 0.f;
        for (int k = ln; k < 200; k += 64)
            a = fmaf(hr[k], Hw2[o * 200 + k], a);
#pragma unroll
        for (int m = 1; m < 64; m <<= 1) a += __shfl_xor(a, m);
        if (ln == 0) lgts[o] = a + Hb2[o];
    }
    __syncthreads();
    if (tid == 0) {
        float m = fmaxf(lgts[0], fmaxf(lgts[1], lgts[2]));
        float e0 = __expf(lgts[0] - m);
        float e1 = __expf(lgts[1] - m);
        float e2 = __expf(lgts[2] - m);
        float s = e0 + e1 + e2;
        out[0] = e0 / s;
        out[1] = e1 / s;
        out[2] = e2 / s;
    }
}

extern "C" void kernel_launch(void* const* d_in, const int* in_sizes, int n_in,
                              void* d_out, int out_size, void* d_ws, size_t ws_size,
                              hipStream_t stream)
{
    const float* sen1 = (const float*)d_in[0];
    const float* sen2 = (const float*)d_in[1];
    const float* F_w1 = (const float*)d_in[2];
    const float* F_b1 = (const float*)d_in[3];
    const float* F_w2 = (const float*)d_in[4];
    const float* F_b2 = (const float*)d_in[5];
    const float* G_w1 = (const float*)d_in[6];
    const float* G_b1 = (const float*)d_in[7];
    const float* G_w2 = (const float*)d_in[8];
    const float* G_b2 = (const float*)d_in[9];
    const float* H_w1 = (const float*)d_in[10];
    const float* H_b1 = (const float*)d_in[11];
    const float* H_w2 = (const float*)d_in[12];
    const float* H_b2 = (const float*)d_in[13];
    float* out = (float*)d_out;

    const int L = 8192;
    char* p = (char*)d_ws;
    ushort* St1  = (ushort*)p; p += (size_t)320 * L * 2;
    ushort* St2  = (ushort*)p; p += (size_t)320 * L * 2;
    ushort* Senb = (ushort*)p; p += (size_t)2 * L * 320 * 2;
    ushort* FaFb = (ushort*)p; p += (size_t)2 * L * 224 * 2;
    ushort* WbF1 = (ushort*)p; p += (size_t)224 * 320 * 2;
    ushort* WbF2 = (ushort*)p; p += (size_t)224 * 224 * 2;
    ushort* WbG1 = (ushort*)p; p += (size_t)224 * 640 * 2;
    ushort* WbG2 = (ushort*)p; p += (size_t)224 * 224 * 2;
    float*  bpF1 = (float*)p;  p += 224 * 4;
    float*  bpF2 = (float*)p;  p += 224 * 4;
    float*  bpG1 = (float*)p;  p += 224 * 4;
    float*  bpG2 = (float*)p;  p += 224 * 4;
    ushort* Pacc = (ushort*)p; p += (size_t)4 * 16384 * 320 * 2;   // 41.94 MB
    float*  Dpart= (float*)p;  p += (size_t)4 * 16384 * 4;         // 262 KB
    float*  Part = (float*)p;  p += (size_t)1024 * 200 * 4;        // 0.82 MB

    // prep: weights (896 blocks) + sen convert/transpose (1280 blocks)
    hipLaunchKernelGGL(prep_kernel, dim3(896 + 1280), dim3(256), 0, stream,
                       sen1, sen2,
                       F_w1, F_b1, F_w2, F_b2, G_w1, G_b1, G_w2, G_b2,
                       Senb, St1, St2,
                       WbF1, bpF1, WbF2, bpF2, WbG1, bpG1, WbG2, bpG2);

    // F MLP -> FaFb bf16
    hipLaunchKernelGGL(mlp2_kernel, dim3(2 * L / 16), dim3(64), 0, stream,
                       Senb, WbF1, bpF1, WbF2, bpF2, FaFb);

    // flash attend, 4-way j-split, 2 blocks/CU
    hipLaunchKernelGGL(attend_mfma_kernel, dim3(512), dim3(512), 0, stream,
                       FaFb, St1, St2, Pacc, Dpart);

    // G MLP (fused 4-slice combine + column partial-sum) -> Part
    hipLaunchKernelGGL(gmlp2_kernel, dim3(2 * L / 16), dim3(64), 0, stream,
                       Senb, Pacc, Dpart, WbG1, bpG1, WbG2, bpG2, Part);

    // fused colsum + head
    hipLaunchKernelGGL(tail_kernel, dim3(1), dim3(1024), 0, stream,
                       Part, H_w1, H_b1, H_w2, H_b2, out);
}

// Round 16
// 286.967 us; speedup vs baseline: 1.2681x; 1.2681x over previous
//
#include <hip/hip_runtime.h>

typedef __attribute__((ext_vector_type(8))) short short8;   // 8 bf16
typedef __attribute__((ext_vector_type(4))) float f32x4;

__device__ inline ushort f2bf(float f) {
    union { float f; unsigned u; } v{f};
    unsigned r = v.u + 0x7FFF + ((v.u >> 16) & 1);
    return (ushort)(r >> 16);
}
__device__ inline float bf2f(ushort u) {
    union { unsigned u; float f; } v;
    v.u = ((unsigned)u) << 16;
    return v.f;
}

// CK-style addrspace casts (low 32 bits of a flat LDS address == LDS offset).
__device__ inline void gload_lds16(const void* g, void* l) {
    __builtin_amdgcn_global_load_lds(
        (const __attribute__((address_space(1))) unsigned int*)(uintptr_t)g,
        (__attribute__((address_space(3))) unsigned int*)(uintptr_t)l,
        16, 0, 0);
}

// ---------------------------------------------------------------------------
// prep: merged weight-convert (blocks 0..895) + sen convert/transpose
// (blocks 896..2175).
// ---------------------------------------------------------------------------
__global__ __launch_bounds__(256) void prep_kernel(
    const float* __restrict__ s1, const float* __restrict__ s2,
    const float* __restrict__ W0, const float* __restrict__ b0,
    const float* __restrict__ W1, const float* __restrict__ b1,
    const float* __restrict__ W2, const float* __restrict__ b2,
    const float* __restrict__ W3, const float* __restrict__ b3,
    ushort* __restrict__ Senb, ushort* __restrict__ St1, ushort* __restrict__ St2,
    ushort* __restrict__ Wb0, float* __restrict__ bp0,
    ushort* __restrict__ Wb1, float* __restrict__ bp1,
    ushort* __restrict__ Wb2, float* __restrict__ bp2,
    ushort* __restrict__ Wb3, float* __restrict__ bp3)
{
    const int bid = blockIdx.x;
    if (bid < 896) {
        const int mat = bid / 224, n = bid % 224;
        if (mat == 2) {   // G1 split layout [224][640]
            for (int k = threadIdx.x; k < 640; k += 256) {
                float v = 0.f;
                if (n < 200) {
                    if (k < 320) { if (k < 300) v = W2[(size_t)n * 600 + k]; }
                    else { int cc = k - 320; if (cc < 300) v = W2[(size_t)n * 600 + 300 + cc]; }
                }
                Wb2[(size_t)n * 640 + k] = f2bf(v);
            }
            if (threadIdx.x == 0) bp2[n] = (n < 200) ? b2[n] : 0.f;
            return;
        }
        const float* W; const float* b; ushort* Wb; float* bp; int N, K, KP;
        if (mat == 0)      { W = W0; b = b0; Wb = Wb0; bp = bp0; N = 200; K = 300; KP = 320; }
        else if (mat == 1) { W = W1; b = b1; Wb = Wb1; bp = bp1; N = 200; K = 200; KP = 224; }
        else               { W = W3; b = b3; Wb = Wb3; bp = bp3; N = 200; K = 200; KP = 224; }
        for (int k = threadIdx.x; k < KP; k += 256)
            Wb[(size_t)n * KP + k] = (n < N && k < K) ? f2bf(W[(size_t)n * K + k]) : (ushort)0;
        if (threadIdx.x == 0) bp[n] = (n < N) ? b[n] : 0.f;
        return;
    }
    // sen path
    const int sb = bid - 896;
    const int gx = sb & 127;
    const int rest = sb >> 7;          // 0..9
    const int gy = rest % 5, gz = rest / 5;
    const float* X = gz ? s2 : s1;
    ushort* Xt = gz ? St2 : St1;
    ushort* Sb = Senb + (size_t)gz * 8192 * 320;
    __shared__ float t[64][65];
    const int r0 = gx * 64, c0 = gy * 64;
    const int tc = threadIdx.x & 63, tr = threadIdx.x >> 6;
    for (int rr = tr; rr < 64; rr += 4) {
        int c = c0 + tc;
        float v = (c < 300) ? X[(size_t)(r0 + rr) * 300 + c] : 0.f;
        t[rr][tc] = v;
        if (c < 320) Sb[(size_t)(r0 + rr) * 320 + c] = f2bf(v);
    }
    __syncthreads();
    for (int rr = tr; rr < 64; rr += 4) {
        int oc = c0 + rr;
        if (oc < 320)
            Xt[(size_t)oc * 8192 + r0 + tc] = f2bf(t[tc][rr]);
    }
}

// ---------------------------------------------------------------------------
// F-MLP: 4-wave blocks, each wave an independent 16-row tile; the 4 waves
// stream the same weights concurrently (L1 reuse: weight traffic /4).
// ---------------------------------------------------------------------------
__global__ __launch_bounds__(256) void mlp2_kernel(
    const ushort* __restrict__ X,
    const ushort* __restrict__ W1, const float* __restrict__ b1,
    const ushort* __restrict__ W2, const float* __restrict__ b2,
    ushort* __restrict__ Ybf)
{
    const int wv = threadIdx.x >> 6;
    const int r0 = (blockIdx.x * 4 + wv) * 16;
    const int lane = threadIdx.x & 63;
    const int lr = lane & 15, lg = lane >> 4;

    __shared__ __align__(16) ushort Y1[4][16][232];

    f32x4 a1[14];
#pragma unroll
    for (int t = 0; t < 14; ++t) a1[t] = f32x4{0.f, 0.f, 0.f, 0.f};

    const ushort* Xrow = X + (size_t)(r0 + lr) * 320 + lg * 8;
    const ushort* W1r  = W1 + (size_t)lr * 320 + lg * 8;
    for (int k0 = 0; k0 < 320; k0 += 32) {
        short8 a = *(const short8*)(Xrow + k0);
#pragma unroll
        for (int t = 0; t < 14; ++t) {
            short8 bfr = *(const short8*)(W1r + (size_t)t * 16 * 320 + k0);
            a1[t] = __builtin_amdgcn_mfma_f32_16x16x32_bf16(a, bfr, a1[t], 0, 0, 0);
        }
    }
#pragma unroll
    for (int t = 0; t < 14; ++t) {
        int col = t * 16 + lr;
        float bv = b1[col];
#pragma unroll
        for (int rr = 0; rr < 4; ++rr)
            Y1[wv][lg * 4 + rr][col] = f2bf(fmaxf(a1[t][rr] + bv, 0.f));
    }
    __syncthreads();

    f32x4 a2[14];
#pragma unroll
    for (int t = 0; t < 14; ++t) a2[t] = f32x4{0.f, 0.f, 0.f, 0.f};
    const ushort* W2r = W2 + (size_t)lr * 224 + lg * 8;
    for (int k0 = 0; k0 < 224; k0 += 32) {
        short8 a = *(const short8*)&Y1[wv][lr][lg * 8 + k0];
#pragma unroll
        for (int t = 0; t < 14; ++t) {
            short8 bfr = *(const short8*)(W2r + (size_t)t * 16 * 224 + k0);
            a2[t] = __builtin_amdgcn_mfma_f32_16x16x32_bf16(a, bfr, a2[t], 0, 0, 0);
        }
    }
#pragma unroll
    for (int t = 0; t < 14; ++t) {
        int col = t * 16 + lr;
        float bv = b2[col];
#pragma unroll
        for (int rr = 0; rr < 4; ++rr) {
            int row = r0 + lg * 4 + rr;
            Ybf[(size_t)row * 224 + col] = f2bf(fmaxf(a2[t][rr] + bv, 0.f));
        }
    }
}

// ---------------------------------------------------------------------------
// G-MLP: 4-wave blocks (weight reuse) + fused 2-slice combine + fused
// column-sum epilogue -> Part[tile][200] f32, tile = blockIdx.x*4 + wv.
// ---------------------------------------------------------------------------
__global__ __launch_bounds__(256) void gmlp2_kernel(
    const ushort* __restrict__ Senb,
    const ushort* __restrict__ Pacc, const float* __restrict__ Dpart,
    const ushort* __restrict__ W1, const float* __restrict__ b1,
    const ushort* __restrict__ W2, const float* __restrict__ b2,
    float* __restrict__ Part)
{
    const int wv = threadIdx.x >> 6;
    const int tile = blockIdx.x * 4 + wv;
    const int r0 = tile * 16;
    const int lane = threadIdx.x & 63;
    const int lr = lane & 15, lg = lane >> 4;
    const int row = r0 + lr;

    __shared__ __align__(16) ushort Y1[4][16][232];

    const float inv = 1.f / (Dpart[row] + Dpart[16384 + row]);
    const ushort* pa = Pacc + (size_t)row * 320;
    const ushort* pb = pa + (size_t)16384 * 320;

    f32x4 a1[14];
#pragma unroll
    for (int t = 0; t < 14; ++t) a1[t] = f32x4{0.f, 0.f, 0.f, 0.f};

    const ushort* Xrow = Senb + (size_t)row * 320 + lg * 8;
    const ushort* W1r  = W1 + (size_t)lr * 640 + lg * 8;
    for (int k0 = 0; k0 < 640; k0 += 32) {
        short8 a;
        if (k0 < 320) {
            a = *(const short8*)(Xrow + k0);
        } else {
            int kk = k0 - 320 + lg * 8;
            short8 x = *(const short8*)(pa + kk);
            short8 y = *(const short8*)(pb + kk);
#pragma unroll
            for (int m = 0; m < 8; ++m)
                a[m] = (short)f2bf((bf2f((ushort)x[m]) + bf2f((ushort)y[m])) * inv);
        }
#pragma unroll
        for (int t = 0; t < 14; ++t) {
            short8 bfr = *(const short8*)(W1r + (size_t)t * 16 * 640 + k0);
            a1[t] = __builtin_amdgcn_mfma_f32_16x16x32_bf16(a, bfr, a1[t], 0, 0, 0);
        }
    }
#pragma unroll
    for (int t = 0; t < 14; ++t) {
        int col = t * 16 + lr;
        float bv = b1[col];
#pragma unroll
        for (int rr = 0; rr < 4; ++rr)
            Y1[wv][lg * 4 + rr][col] = f2bf(fmaxf(a1[t][rr] + bv, 0.f));
    }
    __syncthreads();

    f32x4 a2[14];
#pragma unroll
    for (int t = 0; t < 14; ++t) a2[t] = f32x4{0.f, 0.f, 0.f, 0.f};
    const ushort* W2r = W2 + (size_t)lr * 224 + lg * 8;
    for (int k0 = 0; k0 < 224; k0 += 32) {
        short8 a = *(const short8*)&Y1[wv][lr][lg * 8 + k0];
#pragma unroll
        for (int t = 0; t < 14; ++t) {
            short8 bfr = *(const short8*)(W2r + (size_t)t * 16 * 224 + k0);
            a2[t] = __builtin_amdgcn_mfma_f32_16x16x32_bf16(a, bfr, a2[t], 0, 0, 0);
        }
    }
#pragma unroll
    for (int t = 0; t < 14; ++t) {
        int col = t * 16 + lr;
        if (col < 200) {
            float bv = b2[col];
            float s = 0.f;
#pragma unroll
            for (int rr = 0; rr < 4; ++rr)
                s += fmaxf(a2[t][rr] + bv, 0.f);
            s += __shfl_xor(s, 16);
            s += __shfl_xor(s, 32);
            if (lg == 0)
                Part[(size_t)tile * 200 + col] = s;
        }
    }
}

// ---------------------------------------------------------------------------
// Flash attend — EXACT R13 structure (verified 169.5 us optimum): 2-way
// j-split, 128 Q-rows x 4096 j, 512 thr, Bl+Sl double-buffered LDS staging,
// swapped-E packed P-writes, setprio, bf16 Pacc. Plateau evidence: R10
// barrier-restructure +-0, R12 LDS-diet +1%, R15 Sl-drop/co-residency -45%.
// ---------------------------------------------------------------------------
__global__ __launch_bounds__(512, 2) void attend_mfma_kernel(
    const ushort* __restrict__ FaFb, const ushort* __restrict__ St1,
    const ushort* __restrict__ St2, ushort* __restrict__ Pacc,
    float* __restrict__ Dpart)
{
    const int b = blockIdx.x;
    const int it  = b & 63;
    const int jh  = (b >> 6) & 1;
    const int dir = b >> 7;
    const ushort* A  = FaFb + (dir ? (size_t)8192 * 224 : 0);
    const ushort* B  = FaFb + (dir ? 0 : (size_t)8192 * 224);
    const ushort* St = dir ? St1 : St2;
    const int ib = it * 128;
    const int jo = jh * 4096;

    const int tid = threadIdx.x;
    const int w = tid >> 6;
    const int wi = w >> 1, wj = w & 1;
    const int dq = w & 3,  ih = w >> 2;
    const int lane = tid & 63;
    const int lr = lane & 15, lg = lane >> 4;

    __shared__ __align__(16) ushort Bl[2][28 * 512];
    __shared__ __align__(16) ushort Sl[2][40 * 512];
    __shared__ __align__(16) ushort Pl[128][76];
    __shared__ float dled[8][32];

    f32x4 acc[4][5];
#pragma unroll
    for (int s = 0; s < 4; ++s)
#pragma unroll
        for (int t = 0; t < 5; ++t) acc[s][t] = f32x4{0.f, 0.f, 0.f, 0.f};
    float dsum[2] = {0.f, 0.f};

    short8 afr[2][7];
#pragma unroll
    for (int si = 0; si < 2; ++si) {
        const ushort* Ar = A + (size_t)(ib + wi * 32 + si * 16 + lr) * 224 + lg * 8;
#pragma unroll
        for (int k = 0; k < 7; ++k) afr[si][k] = *(const short8*)(Ar + k * 32);
    }

    const int nB = (w < 4) ? 4 : 3;
    const int pB = (w < 4) ? (w * 4) : (16 + (w - 4) * 3);
    int boff[4];
#pragma unroll
    for (int q = 0; q < 4; ++q) {
        int p = pB + q;
        boff[q] = ((p / 7) * 16 + lr) * 448 + ((p % 7) * 32 + lg * 8) * 2;
    }
    const char* Bb = (const char*)B + (size_t)jo * 448;

    int soff[5];
#pragma unroll
    for (int q = 0; q < 5; ++q) {
        int p = w * 5 + q;
        int srow = p * 8 + (lane >> 3);
        int sl = (lane & 7) ^ (srow & 7);
        soff[q] = srow * 16384 + sl * 16;
    }
    const char* Sb = (const char*)St + (size_t)jo * 2;

    int prow[5], prow7[5];
#pragma unroll
    for (int t = 0; t < 5; ++t) {
        prow[t] = (dq * 80 + t * 16 + lr) * 128;
        prow7[t] = (dq * 80 + t * 16 + lr) & 7;
    }

#pragma unroll
    for (int q = 0; q < 4; ++q)
        if (q < nB) gload_lds16(Bb + boff[q], &Bl[0][(pB + q) * 512]);
#pragma unroll
    for (int q = 0; q < 5; ++q)
        gload_lds16(Sb + soff[q], &Sl[0][(w * 5 + q) * 512]);
    __syncthreads();

    int buf = 0;
    for (int jb = 0; jb < 4096; jb += 64, buf ^= 1) {
        f32x4 e[2][2];
#pragma unroll
        for (int si = 0; si < 2; ++si)
#pragma unroll
            for (int jt = 0; jt < 2; ++jt) e[si][jt] = f32x4{0.f, 0.f, 0.f, 0.f};
        __builtin_amdgcn_s_setprio(1);
#pragma unroll
        for (int kk = 0; kk < 7; ++kk) {
            short8 b0 = *(const short8*)&Bl[buf][((2 * wj + 0) * 7 + kk) * 512 + lane * 8];
            short8 b1 = *(const short8*)&Bl[buf][((2 * wj + 1) * 7 + kk) * 512 + lane * 8];
            e[0][0] = __builtin_amdgcn_mfma_f32_16x16x32_bf16(b0, afr[0][kk], e[0][0], 0, 0, 0);
            e[1][0] = __builtin_amdgcn_mfma_f32_16x16x32_bf16(b0, afr[1][kk], e[1][0], 0, 0, 0);
            e[0][1] = __builtin_amdgcn_mfma_f32_16x16x32_bf16(b1, afr[0][kk], e[0][1], 0, 0, 0);
            e[1][1] = __builtin_amdgcn_mfma_f32_16x16x32_bf16(b1, afr[1][kk], e[1][1], 0, 0, 0);
        }
        __builtin_amdgcn_s_setprio(0);

#pragma unroll
        for (int si = 0; si < 2; ++si) {
#pragma unroll
            for (int jt = 0; jt < 2; ++jt) {
                float x0 = __expf(e[si][jt][0]);
                float x1 = __expf(e[si][jt][1]);
                float x2 = __expf(e[si][jt][2]);
                float x3 = __expf(e[si][jt][3]);
                dsum[si] += (x0 + x1) + (x2 + x3);
                uint2 pk;
                pk.x = (unsigned)f2bf(x0) | ((unsigned)f2bf(x1) << 16);
                pk.y = (unsigned)f2bf(x2) | ((unsigned)f2bf(x3) << 16);
                *(uint2*)&Pl[wi * 32 + si * 16 + lr][wj * 32 + jt * 16 + lg * 4] = pk;
            }
        }
        __syncthreads();

        if (jb + 64 < 4096) {
            const char* Bn = Bb + (size_t)(jb + 64) * 448;
            const char* Sn = Sb + (size_t)(jb + 64) * 2;
#pragma unroll
            for (int q = 0; q < 4; ++q)
                if (q < nB) gload_lds16(Bn + boff[q], &Bl[buf ^ 1][(pB + q) * 512]);
#pragma unroll
            for (int q = 0; q < 5; ++q)
                gload_lds16(Sn + soff[q], &Sl[buf ^ 1][(w * 5 + q) * 512]);
        }

#pragma unroll
        for (int h = 0; h < 2; ++h) {
            short8 pf[4];
#pragma unroll
            for (int s = 0; s < 4; ++s)
                pf[s] = *(const short8*)&Pl[ih * 64 + s * 16 + lr][h * 32 + lg * 8];
            short8 st[5];
#pragma unroll
            for (int t = 0; t < 5; ++t) {
                int sl = ((h << 2) | lg) ^ prow7[t];
                st[t] = *(const short8*)((const char*)Sl[buf] + prow[t] + (sl << 4));
            }
            __builtin_amdgcn_s_setprio(1);
#pragma unroll
            for (int s = 0; s < 4; ++s)
#pragma unroll
                for (int t = 0; t < 5; ++t)
                    acc[s][t] = __builtin_amdgcn_mfma_f32_16x16x32_bf16(pf[s], st[t], acc[s][t], 0, 0, 0);
            __builtin_amdgcn_s_setprio(0);
        }
        __syncthreads();
    }

#pragma unroll
    for (int si = 0; si < 2; ++si) {
        dsum[si] += __shfl_xor(dsum[si], 16);
        dsum[si] += __shfl_xor(dsum[si], 32);
    }
    if (lg == 0) {
#pragma unroll
        for (int si = 0; si < 2; ++si)
            dled[w][si * 16 + lr] = dsum[si];
    }
    __syncthreads();

    if (tid < 128) {
        int wi2 = tid >> 5, idx = tid & 31;
        Dpart[(size_t)jh * 16384 + dir * 8192 + ib + tid] =
            dled[wi2 * 2][idx] + dled[wi2 * 2 + 1][idx];
    }

    ushort* Pb = Pacc + ((size_t)jh * 16384 + dir * 8192 + ib + ih * 64) * 320;
#pragma unroll
    for (int t = 0; t < 5; ++t) {
        int d = dq * 80 + t * 16 + lr;
#pragma unroll
        for (int s = 0; s < 4; ++s)
#pragma unroll
            for (int r = 0; r < 4; ++r)
                Pb[(size_t)(s * 16 + lg * 4 + r) * 320 + d] = f2bf(acc[s][t][r]);
    }
}

// ---------------------------------------------------------------------------
// tail: fused partial-colsum + H head + softmax. One 1024-thread block.
// ---------------------------------------------------------------------------
__global__ __launch_bounds__(1024) void tail_kernel(
    const float* __restrict__ Part,
    const float* __restrict__ Hw1, const float* __restrict__ Hb1,
    const float* __restrict__ Hw2, const float* __restrict__ Hb2,
    float* __restrict__ out)
{
    __shared__ float hpart[800];
    __shared__ float hx[400];
    __shared__ float hr[200];
    __shared__ float lgts[3];
    const int tid = threadIdx.x;

    if (tid < 800) {
        int oc = tid >> 1, ph = tid & 1;
        const float* base = Part + ((size_t)((oc < 200 ? 0 : 512) + ph * 256)) * 200 + (oc % 200);
        float s = 0.f;
        for (int q = 0; q < 256; ++q) s += base[(size_t)q * 200];
        hpart[tid] = s;
    }
    __syncthreads();
    if (tid < 400) hx[tid] = hpart[2 * tid] + hpart[2 * tid + 1];
    __syncthreads();

    {
        int r = tid >> 2, p = tid & 3;
        float a = 0.f;
        if (r < 200) {
            for (int kk = 0; kk < 100; ++kk) {
                int k = p + 4 * kk;
                a = fmaf(hx[k], Hw1[r * 400 + k], a);
            }
        }
        a += __shfl_xor(a, 1);
        a += __shfl_xor(a, 2);
        if (p == 0 && r < 200) hr[r] = fmaxf(a + Hb1[r], 0.f);
    }
    __syncthreads();

    if (tid < 192) {
        int o = tid >> 6, ln = tid & 63;
        float a = 0.f;
        for (int k = ln; k < 200; k += 64)
            a = fmaf(hr[k], Hw2[o * 200 + k], a);
#pragma unroll
        for (int m = 1; m < 64; m <<= 1) a += __shfl_xor(a, m);
        if (ln == 0) lgts[o] = a + Hb2[o];
    }
    __syncthreads();
    if (tid == 0) {
        float m = fmaxf(lgts[0], fmaxf(lgts[1], lgts[2]));
        float e0 = __expf(lgts[0] - m);
        float e1 = __expf(lgts[1] - m);
        float e2 = __expf(lgts[2] - m);
        float s = e0 + e1 + e2;
        out[0] = e0 / s;
        out[1] = e1 / s;
        out[2] = e2 / s;
    }
}

extern "C" void kernel_launch(void* const* d_in, const int* in_sizes, int n_in,
                              void* d_out, int out_size, void* d_ws, size_t ws_size,
                              hipStream_t stream)
{
    const float* sen1 = (const float*)d_in[0];
    const float* sen2 = (const float*)d_in[1];
    const float* F_w1 = (const float*)d_in[2];
    const float* F_b1 = (const float*)d_in[3];
    const float* F_w2 = (const float*)d_in[4];
    const float* F_b2 = (const float*)d_in[5];
    const float* G_w1 = (const float*)d_in[6];
    const float* G_b1 = (const float*)d_in[7];
    const float* G_w2 = (const float*)d_in[8];
    const float* G_b2 = (const float*)d_in[9];
    const float* H_w1 = (const float*)d_in[10];
    const float* H_b1 = (const float*)d_in[11];
    const float* H_w2 = (const float*)d_in[12];
    const float* H_b2 = (const float*)d_in[13];
    float* out = (float*)d_out;

    const int L = 8192;
    char* p = (char*)d_ws;
    ushort* St1  = (ushort*)p; p += (size_t)320 * L * 2;
    ushort* St2  = (ushort*)p; p += (size_t)320 * L * 2;
    ushort* Senb = (ushort*)p; p += (size_t)2 * L * 320 * 2;
    ushort* FaFb = (ushort*)p; p += (size_t)2 * L * 224 * 2;
    ushort* WbF1 = (ushort*)p; p += (size_t)224 * 320 * 2;
    ushort* WbF2 = (ushort*)p; p += (size_t)224 * 224 * 2;
    ushort* WbG1 = (ushort*)p; p += (size_t)224 * 640 * 2;
    ushort* WbG2 = (ushort*)p; p += (size_t)224 * 224 * 2;
    float*  bpF1 = (float*)p;  p += 224 * 4;
    float*  bpF2 = (float*)p;  p += 224 * 4;
    float*  bpG1 = (float*)p;  p += 224 * 4;
    float*  bpG2 = (float*)p;  p += 224 * 4;
    ushort* Pacc = (ushort*)p; p += (size_t)2 * 16384 * 320 * 2;   // 20.97 MB
    float*  Dpart= (float*)p;  p += (size_t)2 * 16384 * 4;         // 131 KB
    float*  Part = (float*)p;  p += (size_t)1024 * 200 * 4;        // 0.82 MB

    // prep: weights (896 blocks) + sen convert/transpose (1280 blocks)
    hipLaunchKernelGGL(prep_kernel, dim3(896 + 1280), dim3(256), 0, stream,
                       sen1, sen2,
                       F_w1, F_b1, F_w2, F_b2, G_w1, G_b1, G_w2, G_b2,
                       Senb, St1, St2,
                       WbF1, bpF1, WbF2, bpF2, WbG1, bpG1, WbG2, bpG2);

    // F MLP (4-wave weight-reuse blocks) -> FaFb bf16
    hipLaunchKernelGGL(mlp2_kernel, dim3(2 * L / 64), dim3(256), 0, stream,
                       Senb, WbF1, bpF1, WbF2, bpF2, FaFb);

    // flash attend (R13 optimum, frozen)
    hipLaunchKernelGGL(attend_mfma_kernel, dim3(256), dim3(512), 0, stream,
                       FaFb, St1, St2, Pacc, Dpart);

    // G MLP (4-wave weight-reuse, fused combine + column partial-sum) -> Part
    hipLaunchKernelGGL(gmlp2_kernel, dim3(2 * L / 64), dim3(256), 0, stream,
                       Senb, Pacc, Dpart, WbG1, bpG1, WbG2, bpG2, Part);

    // fused colsum + head
    hipLaunchKernelGGL(tail_kernel, dim3(1), dim3(1024), 0, stream,
                       Part, H_w1, H_b1, H_w2, H_b2, out);
}

// Round 17
// 275.625 us; speedup vs baseline: 1.3203x; 1.0412x over previous
//
#include <hip/hip_runtime.h>

typedef __attribute__((ext_vector_type(8))) short short8;   // 8 bf16
typedef __attribute__((ext_vector_type(4))) float f32x4;

__device__ inline ushort f2bf(float f) {
    union { float f; unsigned u; } v{f};
    unsigned r = v.u + 0x7FFF + ((v.u >> 16) & 1);
    return (ushort)(r >> 16);
}
__device__ inline float bf2f(ushort u) {
    union { unsigned u; float f; } v;
    v.u = ((unsigned)u) << 16;
    return v.f;
}

// CK-style addrspace casts (low 32 bits of a flat LDS address == LDS offset).
__device__ inline void gload_lds16(const void* g, void* l) {
    __builtin_amdgcn_global_load_lds(
        (const __attribute__((address_space(1))) unsigned int*)(uintptr_t)g,
        (__attribute__((address_space(3))) unsigned int*)(uintptr_t)l,
        16, 0, 0);
}

// ---------------------------------------------------------------------------
// Merged input conversion: sen (f32 [8192][300], z picks sentence) ->
//   Senb bf16 [16384][320] (row-major, zero-padded)
//   St   bf16 [320][8192]  (transposed, pad rows zero)
// ---------------------------------------------------------------------------
__global__ __launch_bounds__(256) void convert_sen_kernel(
    const float* __restrict__ s1, const float* __restrict__ s2,
    ushort* __restrict__ Senb, ushort* __restrict__ St1, ushort* __restrict__ St2)
{
    const float* X = blockIdx.z ? s2 : s1;
    ushort* Xt = blockIdx.z ? St2 : St1;
    ushort* Sb = Senb + (size_t)blockIdx.z * 8192 * 320;
    __shared__ float t[64][65];
    const int r0 = blockIdx.x * 64, c0 = blockIdx.y * 64;
    const int tc = threadIdx.x & 63, tr = threadIdx.x >> 6;
    for (int rr = tr; rr < 64; rr += 4) {
        int c = c0 + tc;
        float v = (c < 300) ? X[(size_t)(r0 + rr) * 300 + c] : 0.f;
        t[rr][tc] = v;
        if (c < 320) Sb[(size_t)(r0 + rr) * 320 + c] = f2bf(v);
    }
    __syncthreads();
    for (int rr = tr; rr < 64; rr += 4) {
        int oc = c0 + rr;
        if (oc < 320)
            Xt[(size_t)oc * 8192 + r0 + tc] = f2bf(t[tc][rr]);
    }
}

// ---------------------------------------------------------------------------
// Weights -> bf16 padded. F1 [224][320], F2 [224][224], G2 [224][224].
// G1 -> [224][640] split-pad: cols 0..319 = sen half, 320..639 = beta half.
// ---------------------------------------------------------------------------
__global__ __launch_bounds__(256) void convert_weights_kernel(
    const float* __restrict__ W0, const float* __restrict__ b0,
    const float* __restrict__ W1, const float* __restrict__ b1,
    const float* __restrict__ W2, const float* __restrict__ b2,
    const float* __restrict__ W3, const float* __restrict__ b3,
    ushort* __restrict__ Wb0, float* __restrict__ bp0,
    ushort* __restrict__ Wb1, float* __restrict__ bp1,
    ushort* __restrict__ Wb2, float* __restrict__ bp2,
    ushort* __restrict__ Wb3, float* __restrict__ bp3)
{
    const int id = blockIdx.x;
    const int mat = id / 224, n = id % 224;
    if (mat == 2) {   // G1 split layout
        for (int k = threadIdx.x; k < 640; k += 256) {
            float v = 0.f;
            if (n < 200) {
                if (k < 320) { if (k < 300) v = W2[(size_t)n * 600 + k]; }
                else { int cc = k - 320; if (cc < 300) v = W2[(size_t)n * 600 + 300 + cc]; }
            }
            Wb2[(size_t)n * 640 + k] = f2bf(v);
        }
        if (threadIdx.x == 0) bp2[n] = (n < 200) ? b2[n] : 0.f;
        return;
    }
    const float* W; const float* b; ushort* Wb; float* bp; int N, K, KP;
    if (mat == 0)      { W = W0; b = b0; Wb = Wb0; bp = bp0; N = 200; K = 300; KP = 320; }
    else if (mat == 1) { W = W1; b = b1; Wb = Wb1; bp = bp1; N = 200; K = 200; KP = 224; }
    else               { W = W3; b = b3; Wb = Wb3; bp = bp3; N = 200; K = 200; KP = 224; }
    for (int k = threadIdx.x; k < KP; k += 256)
        Wb[(size_t)n * KP + k] = (n < N && k < K) ? f2bf(W[(size_t)n * K + k]) : (ushort)0;
    if (threadIdx.x == 0) bp[n] = (n < N) ? b[n] : 0.f;
}

// ---------------------------------------------------------------------------
// Fused 2-layer MLP (F): Y = relu(relu(X@W1^T+b1)@W2^T+b2) -> bf16 [M][224].
// One wave, 16 rows/block (verified best vs K-split R14 and 4-wave R16).
// ---------------------------------------------------------------------------
__global__ __launch_bounds__(64) void mlp2_kernel(
    const ushort* __restrict__ X, int KP1,
    const ushort* __restrict__ W1, const float* __restrict__ b1,
    const ushort* __restrict__ W2, const float* __restrict__ b2,
    ushort* __restrict__ Ybf)
{
    const int r0 = blockIdx.x * 16;
    const int lane = threadIdx.x;
    const int lr = lane & 15, lg = lane >> 4;

    __shared__ __align__(16) ushort Y1[16][232];

    f32x4 a1[14];
#pragma unroll
    for (int t = 0; t < 14; ++t) a1[t] = f32x4{0.f, 0.f, 0.f, 0.f};

    const ushort* Xrow = X + (size_t)(r0 + lr) * KP1 + lg * 8;
    const ushort* W1r  = W1 + (size_t)lr * KP1 + lg * 8;
    for (int k0 = 0; k0 < KP1; k0 += 32) {
        short8 a = *(const short8*)(Xrow + k0);
#pragma unroll
        for (int t = 0; t < 14; ++t) {
            short8 bfr = *(const short8*)(W1r + (size_t)t * 16 * KP1 + k0);
            a1[t] = __builtin_amdgcn_mfma_f32_16x16x32_bf16(a, bfr, a1[t], 0, 0, 0);
        }
    }
#pragma unroll
    for (int t = 0; t < 14; ++t) {
        int col = t * 16 + lr;
        float bv = b1[col];
#pragma unroll
        for (int rr = 0; rr < 4; ++rr)
            Y1[lg * 4 + rr][col] = f2bf(fmaxf(a1[t][rr] + bv, 0.f));
    }
    __syncthreads();

    f32x4 a2[14];
#pragma unroll
    for (int t = 0; t < 14; ++t) a2[t] = f32x4{0.f, 0.f, 0.f, 0.f};
    const ushort* W2r = W2 + (size_t)lr * 224 + lg * 8;
    for (int k0 = 0; k0 < 224; k0 += 32) {
        short8 a = *(const short8*)&Y1[lr][lg * 8 + k0];
#pragma unroll
        for (int t = 0; t < 14; ++t) {
            short8 bfr = *(const short8*)(W2r + (size_t)t * 16 * 224 + k0);
            a2[t] = __builtin_amdgcn_mfma_f32_16x16x32_bf16(a, bfr, a2[t], 0, 0, 0);
        }
    }
#pragma unroll
    for (int t = 0; t < 14; ++t) {
        int col = t * 16 + lr;
        float bv = b2[col];
#pragma unroll
        for (int rr = 0; rr < 4; ++rr) {
            int row = r0 + lg * 4 + rr;
            Ybf[(size_t)row * 224 + col] = f2bf(fmaxf(a2[t][rr] + bv, 0.f));
        }
    }
}

// ---------------------------------------------------------------------------
// G-MLP with FUSED combine (input = [senb | (PaccA+PaccB)*inv], Pacc bf16)
// and FUSED column-sum epilogue -> Part[block][200] f32.
// ---------------------------------------------------------------------------
__global__ __launch_bounds__(64) void gmlp2_kernel(
    const ushort* __restrict__ Senb,
    const ushort* __restrict__ Pacc, const float* __restrict__ Dpart,
    const ushort* __restrict__ W1, const float* __restrict__ b1,
    const ushort* __restrict__ W2, const float* __restrict__ b2,
    float* __restrict__ Part)
{
    const int r0 = blockIdx.x * 16;
    const int lane = threadIdx.x;
    const int lr = lane & 15, lg = lane >> 4;
    const int row = r0 + lr;

    __shared__ __align__(16) ushort Y1[16][232];

    const float inv = 1.f / (Dpart[row] + Dpart[16384 + row]);
    const ushort* pa = Pacc + (size_t)row * 320;
    const ushort* pb = pa + (size_t)16384 * 320;

    f32x4 a1[14];
#pragma unroll
    for (int t = 0; t < 14; ++t) a1[t] = f32x4{0.f, 0.f, 0.f, 0.f};

    const ushort* Xrow = Senb + (size_t)row * 320 + lg * 8;
    const ushort* W1r  = W1 + (size_t)lr * 640 + lg * 8;
    for (int k0 = 0; k0 < 640; k0 += 32) {
        short8 a;
        if (k0 < 320) {
            a = *(const short8*)(Xrow + k0);
        } else {
            int kk = k0 - 320 + lg * 8;
            short8 x = *(const short8*)(pa + kk);
            short8 y = *(const short8*)(pb + kk);
#pragma unroll
            for (int m = 0; m < 8; ++m)
                a[m] = (short)f2bf((bf2f((ushort)x[m]) + bf2f((ushort)y[m])) * inv);
        }
#pragma unroll
        for (int t = 0; t < 14; ++t) {
            short8 bfr = *(const short8*)(W1r + (size_t)t * 16 * 640 + k0);
            a1[t] = __builtin_amdgcn_mfma_f32_16x16x32_bf16(a, bfr, a1[t], 0, 0, 0);
        }
    }
#pragma unroll
    for (int t = 0; t < 14; ++t) {
        int col = t * 16 + lr;
        float bv = b1[col];
#pragma unroll
        for (int rr = 0; rr < 4; ++rr)
            Y1[lg * 4 + rr][col] = f2bf(fmaxf(a1[t][rr] + bv, 0.f));
    }
    __syncthreads();

    f32x4 a2[14];
#pragma unroll
    for (int t = 0; t < 14; ++t) a2[t] = f32x4{0.f, 0.f, 0.f, 0.f};
    const ushort* W2r = W2 + (size_t)lr * 224 + lg * 8;
    for (int k0 = 0; k0 < 224; k0 += 32) {
        short8 a = *(const short8*)&Y1[lr][lg * 8 + k0];
#pragma unroll
        for (int t = 0; t < 14; ++t) {
            short8 bfr = *(const short8*)(W2r + (size_t)t * 16 * 224 + k0);
            a2[t] = __builtin_amdgcn_mfma_f32_16x16x32_bf16(a, bfr, a2[t], 0, 0, 0);
        }
    }
    // relu + column partial-sum over the block's 16 rows -> Part[block][col]
#pragma unroll
    for (int t = 0; t < 14; ++t) {
        int col = t * 16 + lr;
        if (col < 200) {
            float bv = b2[col];
            float s = 0.f;
#pragma unroll
            for (int rr = 0; rr < 4; ++rr)
                s += fmaxf(a2[t][rr] + bv, 0.f);
            s += __shfl_xor(s, 16);
            s += __shfl_xor(s, 32);
            if (lg == 0)
                Part[(size_t)blockIdx.x * 200 + col] = s;
        }
    }
}

// ---------------------------------------------------------------------------
// Flash attend — the verified optimum (R13): 2-way j-split, 128 Q-rows x
// 4096 j per block, 512 thr = 8 waves, grid 256 = 1 block/CU. Bl+Sl
// double-buffered global_load_lds staging, swapped-E packed P-writes,
// setprio, bf16 Pacc. Plateau evidence: R10 barrier-restructure 0,
// R12 LDS-diet +1%, R15 Sl-drop -45%.
// ---------------------------------------------------------------------------
__global__ __launch_bounds__(512, 2) void attend_mfma_kernel(
    const ushort* __restrict__ FaFb, const ushort* __restrict__ St1,
    const ushort* __restrict__ St2, ushort* __restrict__ Pacc,
    float* __restrict__ Dpart)
{
    const int b = blockIdx.x;
    const int it  = b & 63;
    const int jh  = (b >> 6) & 1;
    const int dir = b >> 7;
    const ushort* A  = FaFb + (dir ? (size_t)8192 * 224 : 0);
    const ushort* B  = FaFb + (dir ? 0 : (size_t)8192 * 224);
    const ushort* St = dir ? St1 : St2;
    const int ib = it * 128;
    const int jo = jh * 4096;

    const int tid = threadIdx.x;
    const int w = tid >> 6;
    const int wi = w >> 1, wj = w & 1;
    const int dq = w & 3,  ih = w >> 2;
    const int lane = tid & 63;
    const int lr = lane & 15, lg = lane >> 4;

    __shared__ __align__(16) ushort Bl[2][28 * 512];
    __shared__ __align__(16) ushort Sl[2][40 * 512];
    __shared__ __align__(16) ushort Pl[128][76];
    __shared__ float dled[8][32];

    f32x4 acc[4][5];
#pragma unroll
    for (int s = 0; s < 4; ++s)
#pragma unroll
        for (int t = 0; t < 5; ++t) acc[s][t] = f32x4{0.f, 0.f, 0.f, 0.f};
    float dsum[2] = {0.f, 0.f};

    short8 afr[2][7];
#pragma unroll
    for (int si = 0; si < 2; ++si) {
        const ushort* Ar = A + (size_t)(ib + wi * 32 + si * 16 + lr) * 224 + lg * 8;
#pragma unroll
        for (int k = 0; k < 7; ++k) afr[si][k] = *(const short8*)(Ar + k * 32);
    }

    const int nB = (w < 4) ? 4 : 3;
    const int pB = (w < 4) ? (w * 4) : (16 + (w - 4) * 3);
    int boff[4];
#pragma unroll
    for (int q = 0; q < 4; ++q) {
        int p = pB + q;
        boff[q] = ((p / 7) * 16 + lr) * 448 + ((p % 7) * 32 + lg * 8) * 2;
    }
    const char* Bb = (const char*)B + (size_t)jo * 448;

    int soff[5];
#pragma unroll
    for (int q = 0; q < 5; ++q) {
        int p = w * 5 + q;
        int srow = p * 8 + (lane >> 3);
        int sl = (lane & 7) ^ (srow & 7);
        soff[q] = srow * 16384 + sl * 16;
    }
    const char* Sb = (const char*)St + (size_t)jo * 2;

    int prow[5], prow7[5];
#pragma unroll
    for (int t = 0; t < 5; ++t) {
        prow[t] = (dq * 80 + t * 16 + lr) * 128;
        prow7[t] = (dq * 80 + t * 16 + lr) & 7;
    }

#pragma unroll
    for (int q = 0; q < 4; ++q)
        if (q < nB) gload_lds16(Bb + boff[q], &Bl[0][(pB + q) * 512]);
#pragma unroll
    for (int q = 0; q < 5; ++q)
        gload_lds16(Sb + soff[q], &Sl[0][(w * 5 + q) * 512]);
    __syncthreads();

    int buf = 0;
    for (int jb = 0; jb < 4096; jb += 64, buf ^= 1) {
        f32x4 e[2][2];
#pragma unroll
        for (int si = 0; si < 2; ++si)
#pragma unroll
            for (int jt = 0; jt < 2; ++jt) e[si][jt] = f32x4{0.f, 0.f, 0.f, 0.f};
        __builtin_amdgcn_s_setprio(1);
#pragma unroll
        for (int kk = 0; kk < 7; ++kk) {
            short8 b0 = *(const short8*)&Bl[buf][((2 * wj + 0) * 7 + kk) * 512 + lane * 8];
            short8 b1 = *(const short8*)&Bl[buf][((2 * wj + 1) * 7 + kk) * 512 + lane * 8];
            e[0][0] = __builtin_amdgcn_mfma_f32_16x16x32_bf16(b0, afr[0][kk], e[0][0], 0, 0, 0);
            e[1][0] = __builtin_amdgcn_mfma_f32_16x16x32_bf16(b0, afr[1][kk], e[1][0], 0, 0, 0);
            e[0][1] = __builtin_amdgcn_mfma_f32_16x16x32_bf16(b1, afr[0][kk], e[0][1], 0, 0, 0);
            e[1][1] = __builtin_amdgcn_mfma_f32_16x16x32_bf16(b1, afr[1][kk], e[1][1], 0, 0, 0);
        }
        __builtin_amdgcn_s_setprio(0);

#pragma unroll
        for (int si = 0; si < 2; ++si) {
#pragma unroll
            for (int jt = 0; jt < 2; ++jt) {
                float x0 = __expf(e[si][jt][0]);
                float x1 = __expf(e[si][jt][1]);
                float x2 = __expf(e[si][jt][2]);
                float x3 = __expf(e[si][jt][3]);
                dsum[si] += (x0 + x1) + (x2 + x3);
                uint2 pk;
                pk.x = (unsigned)f2bf(x0) | ((unsigned)f2bf(x1) << 16);
                pk.y = (unsigned)f2bf(x2) | ((unsigned)f2bf(x3) << 16);
                *(uint2*)&Pl[wi * 32 + si * 16 + lr][wj * 32 + jt * 16 + lg * 4] = pk;
            }
        }
        __syncthreads();

        if (jb + 64 < 4096) {
            const char* Bn = Bb + (size_t)(jb + 64) * 448;
            const char* Sn = Sb + (size_t)(jb + 64) * 2;
#pragma unroll
            for (int q = 0; q < 4; ++q)
                if (q < nB) gload_lds16(Bn + boff[q], &Bl[buf ^ 1][(pB + q) * 512]);
#pragma unroll
            for (int q = 0; q < 5; ++q)
                gload_lds16(Sn + soff[q], &Sl[buf ^ 1][(w * 5 + q) * 512]);
        }

#pragma unroll
        for (int h = 0; h < 2; ++h) {
            short8 pf[4];
#pragma unroll
            for (int s = 0; s < 4; ++s)
                pf[s] = *(const short8*)&Pl[ih * 64 + s * 16 + lr][h * 32 + lg * 8];
            short8 st[5];
#pragma unroll
            for (int t = 0; t < 5; ++t) {
                int sl = ((h << 2) | lg) ^ prow7[t];
                st[t] = *(const short8*)((const char*)Sl[buf] + prow[t] + (sl << 4));
            }
            __builtin_amdgcn_s_setprio(1);
#pragma unroll
            for (int s = 0; s < 4; ++s)
#pragma unroll
                for (int t = 0; t < 5; ++t)
                    acc[s][t] = __builtin_amdgcn_mfma_f32_16x16x32_bf16(pf[s], st[t], acc[s][t], 0, 0, 0);
            __builtin_amdgcn_s_setprio(0);
        }
        __syncthreads();
    }

#pragma unroll
    for (int si = 0; si < 2; ++si) {
        dsum[si] += __shfl_xor(dsum[si], 16);
        dsum[si] += __shfl_xor(dsum[si], 32);
    }
    if (lg == 0) {
#pragma unroll
        for (int si = 0; si < 2; ++si)
            dled[w][si * 16 + lr] = dsum[si];
    }
    __syncthreads();

    if (tid < 128) {
        int wi2 = tid >> 5, idx = tid & 31;
        Dpart[(size_t)jh * 16384 + dir * 8192 + ib + tid] =
            dled[wi2 * 2][idx] + dled[wi2 * 2 + 1][idx];
    }

    ushort* Pb = Pacc + ((size_t)jh * 16384 + dir * 8192 + ib + ih * 64) * 320;
#pragma unroll
    for (int t = 0; t < 5; ++t) {
        int d = dq * 80 + t * 16 + lr;
#pragma unroll
        for (int s = 0; s < 4; ++s)
#pragma unroll
            for (int r = 0; r < 4; ++r)
                Pb[(size_t)(s * 16 + lg * 4 + r) * 320 + d] = f2bf(acc[s][t][r]);
    }
}

// ---------------------------------------------------------------------------
// hsum[c] = sum_p Part[half*512 + p][c%200], p in [0,512). c in [0,400).
// ---------------------------------------------------------------------------
__global__ __launch_bounds__(256) void colsum_part_kernel(
    const float* __restrict__ Part, float* __restrict__ hsum)
{
    const int c = blockIdx.x;
    const int base = (c < 200) ? 0 : 512;
    const int col = c % 200;
    float s = 0.f;
    for (int p = threadIdx.x; p < 512; p += 256)
        s += Part[(size_t)(base + p) * 200 + col];
    __shared__ float red[256];
    red[threadIdx.x] = s;
    __syncthreads();
    for (int off = 128; off > 0; off >>= 1) {
        if (threadIdx.x < off) red[threadIdx.x] += red[threadIdx.x + off];
        __syncthreads();
    }
    if (threadIdx.x == 0) hsum[c] = red[0];
}

__global__ __launch_bounds__(256) void head_kernel(
    const float* __restrict__ hsum,
    const float* __restrict__ Hw1, const float* __restrict__ Hb1,
    const float* __restrict__ Hw2, const float* __restrict__ Hb2,
    float* __restrict__ out)
{
    __shared__ float hx[400];
    __shared__ float hr[200];
    __shared__ float lg[3];
    const int t = threadIdx.x;
    for (int i = t; i < 400; i += 256) hx[i] = hsum[i];
    __syncthreads();
    if (t < 200) {
        float a = Hb1[t];
        for (int k = 0; k < 400; ++k) a = fmaf(hx[k], Hw1[t * 400 + k], a);
        hr[t] = fmaxf(a, 0.f);
    }
    __syncthreads();
    if (t < 3) {
        float a = Hb2[t];
        for (int k = 0; k < 200; ++k) a = fmaf(hr[k], Hw2[t * 200 + k], a);
        lg[t] = a;
    }
    __syncthreads();
    if (t == 0) {
        float m = fmaxf(lg[0], fmaxf(lg[1], lg[2]));
        float e0 = __expf(lg[0] - m);
        float e1 = __expf(lg[1] - m);
        float e2 = __expf(lg[2] - m);
        float s = e0 + e1 + e2;
        out[0] = e0 / s;
        out[1] = e1 / s;
        out[2] = e2 / s;
    }
}

extern "C" void kernel_launch(void* const* d_in, const int* in_sizes, int n_in,
                              void* d_out, int out_size, void* d_ws, size_t ws_size,
                              hipStream_t stream)
{
    const float* sen1 = (const float*)d_in[0];
    const float* sen2 = (const float*)d_in[1];
    const float* F_w1 = (const float*)d_in[2];
    const float* F_b1 = (const float*)d_in[3];
    const float* F_w2 = (const float*)d_in[4];
    const float* F_b2 = (const float*)d_in[5];
    const float* G_w1 = (const float*)d_in[6];
    const float* G_b1 = (const float*)d_in[7];
    const float* G_w2 = (const float*)d_in[8];
    const float* G_b2 = (const float*)d_in[9];
    const float* H_w1 = (const float*)d_in[10];
    const float* H_b1 = (const float*)d_in[11];
    const float* H_w2 = (const float*)d_in[12];
    const float* H_b2 = (const float*)d_in[13];
    float* out = (float*)d_out;

    const int L = 8192;
    char* p = (char*)d_ws;
    ushort* St1  = (ushort*)p; p += (size_t)320 * L * 2;
    ushort* St2  = (ushort*)p; p += (size_t)320 * L * 2;
    ushort* Senb = (ushort*)p; p += (size_t)2 * L * 320 * 2;
    ushort* FaFb = (ushort*)p; p += (size_t)2 * L * 224 * 2;
    ushort* WbF1 = (ushort*)p; p += (size_t)224 * 320 * 2;
    ushort* WbF2 = (ushort*)p; p += (size_t)224 * 224 * 2;
    ushort* WbG1 = (ushort*)p; p += (size_t)224 * 640 * 2;
    ushort* WbG2 = (ushort*)p; p += (size_t)224 * 224 * 2;
    float*  bpF1 = (float*)p;  p += 224 * 4;
    float*  bpF2 = (float*)p;  p += 224 * 4;
    float*  bpG1 = (float*)p;  p += 224 * 4;
    float*  bpG2 = (float*)p;  p += 224 * 4;
    float*  hsum = (float*)p;  p += 400 * 4;
    ushort* Pacc = (ushort*)p; p += (size_t)2 * 16384 * 320 * 2;
    float*  Dpart= (float*)p;  p += (size_t)2 * 16384 * 4;
    float*  Part = (float*)p;  p += (size_t)1024 * 200 * 4;

    dim3 blk256(256);

    // merged input convert + transpose
    hipLaunchKernelGGL(convert_sen_kernel, dim3(L / 64, 5, 2), blk256, 0, stream,
                       sen1, sen2, Senb, St1, St2);
    hipLaunchKernelGGL(convert_weights_kernel, dim3(4 * 224), blk256, 0, stream,
                       F_w1, F_b1, F_w2, F_b2, G_w1, G_b1, G_w2, G_b2,
                       WbF1, bpF1, WbF2, bpF2, WbG1, bpG1, WbG2, bpG2);

    // F MLP fused (both sentences, M = 16384) -> FaFb bf16
    hipLaunchKernelGGL(mlp2_kernel, dim3(2 * L / 16), dim3(64), 0, stream,
                       Senb, 320, WbF1, bpF1, WbF2, bpF2, FaFb);

    // flash attend, j-split partials (128-row blocks, 512 threads)
    hipLaunchKernelGGL(attend_mfma_kernel, dim3(256), dim3(512), 0, stream,
                       FaFb, St1, St2, Pacc, Dpart);

    // G MLP with fused combine + fused column partial-sum -> Part
    hipLaunchKernelGGL(gmlp2_kernel, dim3(2 * L / 16), dim3(64), 0, stream,
                       Senb, Pacc, Dpart, WbG1, bpG1, WbG2, bpG2, Part);

    // reduce partials -> hsum[400], then head
    hipLaunchKernelGGL(colsum_part_kernel, dim3(400), blk256, 0, stream, Part, hsum);
    hipLaunchKernelGGL(head_kernel, dim3(1), blk256, 0, stream,
                       hsum, H_w1, H_b1, H_w2, H_b2, out);
}